// Round 1
// 548.818 us; speedup vs baseline: 1.0084x; 1.0084x over previous
//
#include <hip/hip_runtime.h>

// out[t, n*16+f] = relu(bias[f] + sum_{l=0}^{31} x[t-1-2l, n] * w_pn[l, f])
// w_pn = relu(w) / ||relu(w)||_2 (per filter column, over 32 lags)
//
// T=2048, N=4096 inputs, L=32 lags, F=16 filters, dilation=2.
//
// Occupancy redesign vs prior version: thread owns (n_local, filter-PAIR),
// so weights cost 64 VGPRs instead of 128 -> 4 waves/SIMD (was 2).
// x tile lives in LDS parity-split and TRANSPOSED (sxT[p][n][row], pitch 68)
// so the per-group lag window is 10 ds_read_b128 (conflict-free: bank =
// 4*(n&7) + r spreads the 8 distinct wave addresses across all 32 banks)
// instead of 35 strided ds_read_b32.

constexpr int T = 2048;
constexpr int N = 4096;
constexpr int L = 32;
constexpr int F = 16;
constexpr int BT = 64;            // t rows per block
constexpr int BN = 32;            // n cols per block
constexpr int RP = 68;            // per-parity row pitch (64 rows + pad -> bank spread)
constexpr int OUT_STRIDE = N * F; // 65536

typedef float f4 __attribute__((ext_vector_type(4)));
typedef float f2 __attribute__((ext_vector_type(2)));

__global__ __launch_bounds__(256, 4)
void tlayer_kernel(const float* __restrict__ x,
                   const float* __restrict__ w,
                   const float* __restrict__ bias,
                   float* __restrict__ out)
{
    // [parity][col][row]: row = per-parity t index. 2*32*68*4 = 17408 B
    __shared__ __align__(16) float sxT[2 * BN * RP];
    __shared__ float sw[L * F];       // 2048 B
    __shared__ float sscale[F];

    const int tid = threadIdx.x;
    const int n0  = blockIdx.x * BN;
    const int t0  = blockIdx.y * BT;

    // ---- weight prep (redundant per block; 512 elements, trivial) ----
    sw[tid]       = fmaxf(w[tid], 0.f);
    sw[tid + 256] = fmaxf(w[tid + 256], 0.f);
    __syncthreads();
    if (tid < F) {
        float s = 0.f;
        #pragma unroll
        for (int l = 0; l < L; ++l) { float v = sw[l * F + tid]; s += v * v; }
        sscale[tid] = rsqrtf(fmaxf(s, 1e-12f));
    }
    __syncthreads();
    sw[tid]       *= sscale[tid & 15];
    sw[tid + 256] *= sscale[tid & 15];

    // ---- stage x rows t0-63 .. t0+62 transposed into sxT ----
    // global row g -> rel = g-(t0-63) in [0,126), parity p = rel&1, row rr = rel>>1
    for (int idx = tid; idx < 126 * (BN / 4); idx += 256) {
        const int r  = idx >> 3;               // 0..125
        const int c4 = idx & 7;                // float4 column group
        const int g  = t0 - 63 + r;
        f4 v = {0.f, 0.f, 0.f, 0.f};
        if (g >= 0 && g < T)
            v = *(const f4*)(x + (size_t)g * N + n0 + c4 * 4);
        const int p  = r & 1;
        const int rr = r >> 1;                 // 0..62 (row 63 stays garbage, never used)
        float* dst = sxT + p * (BN * RP) + (c4 * 4) * RP + rr;
        dst[0 * RP] = v[0];
        dst[1 * RP] = v[1];
        dst[2 * RP] = v[2];
        dst[3 * RP] = v[3];
    }
    __syncthreads();

    const int fp = tid & 7;            // filter pair: f = 2*fp, 2*fp+1
    const int nl = tid >> 3;           // 0..31 local input unit
    const f2 b2 = *(const f2*)(bias + fp * 2);

    // weights for my 2 filters -> 64 VGPRs
    f2 wr[L];
    #pragma unroll
    for (int l = 0; l < L; ++l)
        wr[l] = *(const f2*)(sw + l * F + fp * 2);

    const float* myrow = sxT + nl * RP;
    float* outbase = out + (size_t)(n0 + nl) * F + fp * 2;

    // 16 groups of 4 same-parity t's cover the 64-t tile.
    // Group grp: t = t0 + toff + 2j, j=0..3; needs xv[m] = x-row (toff+2m),
    // i.e. per-parity rows r0p..r0p+34 (r0p = toff>>1, multiple of 4).
    #pragma unroll 1
    for (int grp = 0; grp < 16; ++grp) {
        const int toff = (grp & 1) + (grp >> 1) * 8;
        const int p    = grp & 1;
        const int r0p  = (grp >> 1) * 4;
        const float* src = myrow + p * (BN * RP) + r0p;

        f2 acc[4] = {b2, b2, b2, b2};

        // phase A: xv[0..18] (rows r0p..r0p+19), serves l = 16..31
        f4 xa[5];
        #pragma unroll
        for (int u = 0; u < 5; ++u)
            xa[u] = *(const f4*)(src + 4 * u);

        #pragma unroll
        for (int l = 16; l < 32; ++l) {
            const f2 wl = wr[l];
            #pragma unroll
            for (int j = 0; j < 4; ++j) {
                const int m = 31 + j - l;          // 0..18, compile-time
                acc[j] += wl * xa[m >> 2][m & 3];
            }
        }

        // phase B: xv[16..34] (rows r0p+16..r0p+35), serves l = 0..15
        f4 xb[5];
        #pragma unroll
        for (int u = 0; u < 5; ++u)
            xb[u] = *(const f4*)(src + 16 + 4 * u);

        #pragma unroll
        for (int l = 0; l < 16; ++l) {
            const f2 wl = wr[l];
            #pragma unroll
            for (int j = 0; j < 4; ++j) {
                const int k = 15 + j - l;          // 0..18, compile-time
                acc[j] += wl * xb[k >> 2][k & 3];
            }
        }

        #pragma unroll
        for (int j = 0; j < 4; ++j) {
            f2 r;
            r[0] = fmaxf(acc[j][0], 0.f);
            r[1] = fmaxf(acc[j][1], 0.f);
            __builtin_nontemporal_store(
                r, (f2*)(outbase + (size_t)(t0 + toff + 2 * j) * OUT_STRIDE));
        }
    }
}

extern "C" void kernel_launch(void* const* d_in, const int* in_sizes, int n_in,
                              void* d_out, int out_size, void* d_ws, size_t ws_size,
                              hipStream_t stream) {
    const float* x    = (const float*)d_in[0];   // [2048, 4096]
    const float* w    = (const float*)d_in[1];   // [32, 16]
    const float* bias = (const float*)d_in[2];   // [16]
    float* out = (float*)d_out;                  // [2048, 65536]

    dim3 grid(N / BN, T / BT);                   // (128, 32)
    tlayer_kernel<<<grid, 256, 0, stream>>>(x, w, bias, out);
}